// Round 5
// baseline (103.666 us; speedup 1.0000x reference)
//
#include <hip/hip_runtime.h>

#define N 1024
#define E 256
#define H 128

typedef _Float16 half_t;
typedef _Float16 hv2 __attribute__((ext_vector_type(2)));
typedef _Float16 hv4 __attribute__((ext_vector_type(4)));

__device__ __forceinline__ float dot2_acc(hv2 a, hv2 b, float c) {
#if __has_builtin(__builtin_amdgcn_fdot2)
    return __builtin_amdgcn_fdot2(a, b, c, false);
#else
    return c + (float)a.x * (float)b.x + (float)a.y * (float)b.y;
#endif
}

__device__ __forceinline__ hv2 relu_add2(hv2 a, hv2 b) {
    hv2 s = a + b;
    hv2 z = (hv2)(_Float16)0.f;
    return __builtin_elementwise_max(s, z);
}

// Setup: blocks 0..127 compute rows 2b,2b+1 of Wq' = Wq@W1a (t<128) and
// Wk' = Wk@W1b (t>=128), written f16 into the e-quad-packed layout
// (hv4 at [e/4][h]; this block writes the lo or hi hv2 of quad e4=b>>1).
// Block 128: ctx = relu(x@Wc+bc); constq=(bq+ctx)@W1a+b1; constk=(bk+ctx)@W1b.
__global__ __launch_bounds__(256) void setup_kernel(
    const float* __restrict__ x, const float* __restrict__ Wc, const float* __restrict__ bc,
    const float* __restrict__ Wq, const float* __restrict__ bq,
    const float* __restrict__ Wk, const float* __restrict__ bk,
    const float* __restrict__ W1, const float* __restrict__ b1,
    hv2* __restrict__ Wqp2, hv2* __restrict__ Wkp2,
    float* __restrict__ constq, float* __restrict__ constk) {
    int b = blockIdx.x;
    int t = threadIdx.x;
    if (b < E / 2) {
        __shared__ float wq_s[2][H], wk_s[2][H];
        {
            int r = t >> 7, c = t & 127;
            wq_s[r][c] = Wq[(2 * b + r) * H + c];
            wk_s[r][c] = Wk[(2 * b + r) * H + c];
        }
        __syncthreads();
        int h = t & 127;
        bool isq = t < H;
        const float* M = isq ? W1 : (W1 + H * H);
        const float* w0 = isq ? wq_s[0] : wk_s[0];
        const float* w1r = isq ? wq_s[1] : wk_s[1];
        float a0 = 0.f, a1 = 0.f;
#pragma unroll 4
        for (int r = 0; r < H; ++r) {
            float m = M[r * H + h];
            a0 += w0[r] * m;
            a1 += w1r[r] * m;
        }
        hv2 o; o.x = (half_t)a0; o.y = (half_t)a1;
        hv2* O = isq ? Wqp2 : Wkp2;
        O[((b >> 1) * H + h) * 2 + (b & 1)] = o;
    } else {
        __shared__ float xs[E];
        __shared__ float pc[2][H];
        __shared__ float aq_s[H], ak_s[H];
        xs[t] = x[t];
        __syncthreads();
        int h = t & (H - 1);
        int c = t >> 7;  // 0 or 1
        float p = 0.f;
#pragma unroll 8
        for (int e = c * H; e < c * H + H; ++e) p += xs[e] * Wc[e * H + h];
        pc[c][h] = p;
        __syncthreads();
        if (t < H) {
            float ctxv = fmaxf(pc[0][t] + pc[1][t] + bc[t], 0.f);
            aq_s[t] = bq[t] + ctxv;
            ak_s[t] = bk[t] + ctxv;
        }
        __syncthreads();
        float acc;
        if (t < H) {
            acc = b1[h];
#pragma unroll 8
            for (int r = 0; r < H; ++r) acc += aq_s[r] * W1[r * H + h];
            constq[h] = acc;
        } else {
            acc = 0.f;
#pragma unroll 8
            for (int r = 0; r < H; ++r) acc += ak_s[r] * W1[(H + r) * H + h];
            constk[h] = acc;
        }
    }
}

// proj: 4 rows per block. qp[i] = P[i]@Wq' + constq (f16 out); kp likewise.
// Wq'/Wk' read f16 quad-packed (hv4 b64 loads, coalesced); P staged f16 in
// LDS quad-transposed; fdot2 accumulate in f32.
__global__ __launch_bounds__(256) void proj_kernel(
    const float* __restrict__ P,
    const hv4* __restrict__ Wqp4, const hv4* __restrict__ Wkp4,
    const float* __restrict__ constq, const float* __restrict__ constk,
    half_t* __restrict__ qh, half_t* __restrict__ kh) {
    __shared__ __align__(16) hv4 ps4[64][4];   // [e4][row]
    int b = blockIdx.x;
    int i0 = b * 4;
    int t = threadIdx.x;
    {
        int row = t >> 6, e4 = t & 63;
        float4 v = ((const float4*)(P + (i0 + row) * E))[e4];
        hv4 o; o.x = (half_t)v.x; o.y = (half_t)v.y; o.z = (half_t)v.z; o.w = (half_t)v.w;
        ps4[e4][row] = o;
    }
    __syncthreads();
    bool isq = t < H;
    int h = t & (H - 1);
    const hv4* M = isq ? Wqp4 : Wkp4;
    float cv = isq ? constq[h] : constk[h];
    float a0 = cv, a1 = cv, a2 = cv, a3 = cv;
    for (int e4 = 0; e4 < 64; ++e4) {
        hv4 m = M[e4 * H + h];                 // b64 global, coalesced
        const hv2* m2 = (const hv2*)&m;
        hv4 p0 = ps4[e4][0], p1 = ps4[e4][1], p2 = ps4[e4][2], p3 = ps4[e4][3];
        const hv2* q0 = (const hv2*)&p0;
        const hv2* q1 = (const hv2*)&p1;
        const hv2* q2 = (const hv2*)&p2;
        const hv2* q3 = (const hv2*)&p3;
        a0 = dot2_acc(q0[0], m2[0], a0); a0 = dot2_acc(q0[1], m2[1], a0);
        a1 = dot2_acc(q1[0], m2[0], a1); a1 = dot2_acc(q1[1], m2[1], a1);
        a2 = dot2_acc(q2[0], m2[0], a2); a2 = dot2_acc(q2[1], m2[1], a2);
        a3 = dot2_acc(q3[0], m2[0], a3); a3 = dot2_acc(q3[1], m2[1], a3);
    }
    half_t* O = isq ? qh : kh;
    O[(i0 + 0) * H + h] = (half_t)a0;
    O[(i0 + 1) * H + h] = (half_t)a1;
    O[(i0 + 2) * H + h] = (half_t)a2;
    O[(i0 + 3) * H + h] = (half_t)a3;
}

// pair: exact triangular tiling. 528 blocks, one 32x32 (bi<=bj) tile each.
// Per thread: 4 (i,j) pairs; f16 LDS + fdot2; W2 held in registers.
#define QSTR 136  // halves; 272 B row stride -> odd count of 16B superbanks -> conflict-free b128
__global__ __launch_bounds__(256) void pair_kernel(
    const half_t* __restrict__ qh, const half_t* __restrict__ kh,
    const float* __restrict__ W2, const float* __restrict__ b2,
    float* __restrict__ out) {
    // map linear tile id -> (bi, bj), bi <= bj, row-major upper-tri incl diag
    int tid = blockIdx.x;
    int bi = (int)((65.0f - sqrtf(4225.0f - 8.0f * (float)tid)) * 0.5f);
    while (bi > 0 && tid < 32 * bi - bi * (bi - 1) / 2) --bi;
    while (tid >= 32 * (bi + 1) - (bi + 1) * bi / 2) ++bi;
    int bj = bi + (tid - (32 * bi - bi * (bi - 1) / 2));

    __shared__ __align__(16) half_t qs[32][QSTR];
    __shared__ __align__(16) half_t ks[32][QSTR];
    __shared__ __align__(16) half_t w2s[H];

    int t = threadIdx.x;
    if (t < H) w2s[t] = (half_t)W2[t];

    const float4* qh4 = (const float4*)(qh + bi * 32 * H);
    const float4* kh4 = (const float4*)(kh + bj * 32 * H);
#pragma unroll
    for (int v = 0; v < 2; ++v) {
        int idx = v * 256 + t;           // 0..511 : 32 rows x 16 float4
        int r = idx >> 4, c = idx & 15;
        float4 q = qh4[idx];
        float4 k = kh4[idx];
        *(float4*)&qs[r][c * 8] = q;
        *(float4*)&ks[r][c * 8] = k;
    }
    __syncthreads();

    // hoist W2 into registers (16 x float4 = 16 x 4 hv2)
    float4 wreg[16];
#pragma unroll
    for (int h8 = 0; h8 < 16; ++h8) wreg[h8] = *(const float4*)&w2s[h8 * 8];

    int jj  = t & 31;    // k row within tile
    int ti0 = t >> 5;    // q rows ti0, ti0+8, ti0+16, ti0+24
    float b2v = b2[0];
    float acc[4];
#pragma unroll
    for (int u = 0; u < 4; ++u) acc[u] = b2v;

    for (int h8 = 0; h8 < 16; ++h8) {
        float4 kv = *(const float4*)&ks[jj][h8 * 8];
        const hv2* wp = (const hv2*)&wreg[h8];
        const hv2* kp2 = (const hv2*)&kv;
#pragma unroll
        for (int u = 0; u < 4; ++u) {
            float4 qf = *(const float4*)&qs[ti0 + u * 8][h8 * 8];
            const hv2* qp2 = (const hv2*)&qf;
#pragma unroll
            for (int s = 0; s < 4; ++s) {
                hv2 sa = relu_add2(qp2[s], kp2[s]);
                acc[u] = dot2_acc(sa, wp[s], acc[u]);
            }
        }
    }

#pragma unroll
    for (int u = 0; u < 4; ++u) {
        int i = bi * 32 + ti0 + u * 8;
        int j = bj * 32 + jj;
        if (j > i) {
            int base = i * (2 * N - i - 1) / 2;
            out[base + (j - i - 1)] = acc[u];
        }
    }
}

extern "C" void kernel_launch(void* const* d_in, const int* in_sizes, int n_in,
                              void* d_out, int out_size, void* d_ws, size_t ws_size,
                              hipStream_t stream) {
    const float* x  = (const float*)d_in[0];
    const float* P  = (const float*)d_in[1];
    const float* Wq = (const float*)d_in[2];
    const float* bq = (const float*)d_in[3];
    const float* Wk = (const float*)d_in[4];
    const float* bk = (const float*)d_in[5];
    const float* Wc = (const float*)d_in[6];
    const float* bc = (const float*)d_in[7];
    const float* W1 = (const float*)d_in[8];
    const float* b1 = (const float*)d_in[9];
    const float* W2 = (const float*)d_in[10];
    const float* b2 = (const float*)d_in[11];
    float* out = (float*)d_out;

    float* ws     = (float*)d_ws;
    float* constq = ws;                        // 128 f32
    float* constk = ws + H;                    // 128 f32
    hv4* Wqp4     = (hv4*)(ws + 2 * H);        // 64*128 hv4 = 64 KB
    hv4* Wkp4     = Wqp4 + (E / 4) * H;        // 64 KB
    half_t* qh    = (half_t*)(Wkp4 + (E / 4) * H);  // 1024*128 halves
    half_t* kh    = qh + N * H;                     // 1024*128 halves

    setup_kernel<<<E / 2 + 1, 256, 0, stream>>>(x, Wc, bc, Wq, bq, Wk, bk, W1, b1,
                                                (hv2*)Wqp4, (hv2*)Wkp4, constq, constk);
    proj_kernel<<<N / 4, 256, 0, stream>>>(P, Wqp4, Wkp4, constq, constk, qh, kh);
    pair_kernel<<<528, 256, 0, stream>>>(qh, kh, W2, b2, out);
}